// Round 13
// baseline (338.462 us; speedup 1.0000x reference)
//
#include <hip/hip_runtime.h>
#include <hip/hip_bf16.h>

// (B, nf, D, H, W) = (4, 48, 12, 56, 56), fp32 in/out, bf16 MFMA internally.
// Sampled tensors: SIX bf16 chunk-planes [6][NLOC][8ch] (16B/pixel stride).
// Round 13: round-10 structure (64 loc/wave, 2-way tap split, packed-f32
// interp) + SOFTWARE PIPELINING: each iteration issues the NEXT tap's 24
// gathers (and offsets 2 taps ahead) before the current tap's MFMA, so the
// ~400cy gather latency is hidden under MFMA+interp. Rounds 9/11/12 proved
// more waves don't help (VALU+L1 are shared-pipe co-bound at 2 waves/SIMD);
// this overlaps the two pipes within a wave instead.
constexpr int B_ = 4, C_ = 48, D_ = 12, H_ = 56, W_ = 56;
constexpr int DHW_ = D_ * H_ * W_;        // 37632
constexpr int NLOC_ = B_ * DHW_;          // 150528 -> 2352 blocks of 128
constexpr int OFFC_ = 54;                 // 27 taps x 2 (dh, dw)
constexpr int NXCD_ = 8;

typedef short bf16x8 __attribute__((ext_vector_type(8)));
typedef float f32x4  __attribute__((ext_vector_type(4)));
typedef float f32x2  __attribute__((ext_vector_type(2)));
typedef unsigned int u32x4 __attribute__((ext_vector_type(4)));
typedef unsigned int u32x2 __attribute__((ext_vector_type(2)));

__device__ __forceinline__ int xcd_swizzle(int bid, int nwg) {
    int xcd = bid % NXCD_, lid = bid / NXCD_;
    int q = nwg / NXCD_, r = nwg % NXCD_;
    return (xcd < r ? xcd * (q + 1) : r * (q + 1) + (xcd - r) * q) + lid;
}

__device__ __forceinline__ unsigned int f2bf_u(float f) {
    __hip_bfloat16 h = __float2bfloat16(f);
    return (unsigned int)__builtin_bit_cast(unsigned short, h);
}

__device__ __forceinline__ f32x2 bfpair(unsigned int pv) {
    f32x2 r;
    r.x = __builtin_bit_cast(float, pv << 16);
    r.y = __builtin_bit_cast(float, pv & 0xffff0000u);
    return r;
}
__device__ __forceinline__ f32x2 pk_mul(f32x2 a, f32x2 b) {
    f32x2 d;
    asm("v_pk_mul_f32 %0, %1, %2" : "=v"(d) : "v"(a), "v"(b));
    return d;
}
__device__ __forceinline__ f32x2 pk_fma(f32x2 a, f32x2 b, f32x2 c) {
    f32x2 d;
    asm("v_pk_fma_f32 %0, %1, %2, %3" : "=v"(d) : "v"(a), "v"(b), "v"(c));
    return d;
}
__device__ __forceinline__ unsigned int cvt_pk_bf16(float lo, float hi) {
    unsigned int r;
    asm("v_cvt_pk_bf16_f32 %0, %1, %2" : "=v"(r) : "v"(lo), "v"(hi));
    return r;
}

// 4-corner bilinear on a 16B chunk (8 bf16 channels), packed-f32 math.
__device__ __forceinline__ u32x4 interp4_pk(u32x4 c00, u32x4 c01, u32x4 c10, u32x4 c11,
                                            f32x2 w0, f32x2 w1, f32x2 w2, f32x2 w3) {
    u32x4 pv;
#pragma unroll
    for (int u = 0; u < 4; ++u) {
        f32x2 r = pk_mul(w0, bfpair(c00[u]));
        r = pk_fma(w1, bfpair(c01[u]), r);
        r = pk_fma(w2, bfpair(c10[u]), r);
        r = pk_fma(w3, bfpair(c11[u]), r);
        pv[u] = cvt_pk_bf16(r.x, r.y);
    }
    return pv;
}

// Pack weights into MFMA A-fragment order (bf16):
// wf[k][mt][ks][lane][i] = W[oc=mt*16+(lane&15)][c=ks*32+8*(lane>>4)+i][tap k]
__global__ void __launch_bounds__(256) repack_frag_kernel(
    const float* __restrict__ w, unsigned short* __restrict__ wf, int OC, int MT) {
    int t = blockIdx.x * 256 + threadIdx.x;
    int total = 27 * MT * 1024;
    if (t >= total) return;
    int i    = t & 7;
    int lane = (t >> 3) & 63;
    int ks   = (t >> 9) & 1;
    int mt   = (t >> 10) % MT;
    int k    = t / (MT << 10);
    int oc = mt * 16 + (lane & 15);
    int c  = ks * 32 + 8 * (lane >> 4) + i;
    float v = (oc < OC && c < 48) ? w[((size_t)oc * 48 + c) * 27 + k] : 0.0f;
    wf[t] = (unsigned short)f2bf_u(v);
}

// fp32 [B][48][DHW] -> bf16 chunk-planes [6][NLOC][8].
__global__ void __launch_bounds__(256) to_cl_kernel(const float* __restrict__ x,
                                                    unsigned short* __restrict__ xcl) {
    int loc = blockIdx.x * 256 + threadIdx.x;
    int b = loc / DHW_, s = loc - b * DHW_;
    const float* xp = x + (size_t)b * (C_ * DHW_) + s;
#pragma unroll
    for (int q = 0; q < 6; ++q) {
        float v[8];
#pragma unroll
        for (int u = 0; u < 8; ++u) v[u] = xp[(size_t)(q * 8 + u) * DHW_];
        u32x4 o;
#pragma unroll
        for (int u = 0; u < 4; ++u)
            o[u] = cvt_pk_bf16(v[2 * u], v[2 * u + 1]);
        *(u32x4*)(xcl + ((size_t)q * NLOC_ + loc) * 8) = o;   // 16B/lane dense
    }
}

// ---------------- offset conv (plain 3x3x3, 54 outputs) via MFMA ----------------
// 2 waves share 64 locations; wave w does taps k === w (mod 2). Next tap's 6
// chunk loads are issued before the current tap's MFMA (software pipeline).
__global__ void __launch_bounds__(128) offconv_mfma(
    const unsigned short* __restrict__ xcl,   // [6][NLOC][8] bf16 chunk-planes
    const unsigned short* __restrict__ wf,    // frag-packed, MT=4
    const float* __restrict__ bo,             // [54]
    float* __restrict__ off) {                // [B][54][DHW] fp32
    __shared__ unsigned short S[2][64][64];
    int tid = threadIdx.x, wid = tid >> 6, lane = tid & 63;
    int base = xcd_swizzle(blockIdx.x, gridDim.x) * 64;
    int loc = base + lane;
    int b = loc / DHW_;
    int sp = loc - b * DHW_;
    int w = sp % W_; int t1 = sp / W_;
    int h = t1 % H_; int d = t1 / H_;
    int g = lane >> 4, li = lane & 15, l7 = lane & 7;

    u32x4 z = {0, 0, 0, 0};
    *(u32x4*)&S[wid][lane][(6 ^ l7) * 8] = z;   // K-pad channels 48..63
    *(u32x4*)&S[wid][lane][(7 ^ l7) * 8] = z;

    f32x4 acc[4][4];
#pragma unroll
    for (int mt = 0; mt < 4; ++mt)
#pragma unroll
        for (int nt = 0; nt < 4; ++nt) acc[mt][nt] = (f32x4){0.f, 0.f, 0.f, 0.f};

    const u32x4* plane[6];
#pragma unroll
    for (int q = 0; q < 6; ++q)
        plane[q] = (const u32x4*)(xcl + ((size_t)q * NLOC_ + (size_t)b * DHW_) * 8);

    // ---- pipeline prologue: tap k0 meta + gathers ----
    int k = wid;
    u32x4 pv[6];
    bool valid;
    {
        int kd = k / 9 - 1, kh = (k / 3) % 3 - 1, kw = k % 3 - 1;
        int pd = d + kd, ph = h + kh, pw = w + kw;
        valid = (pd >= 0) & (pd < D_) & (ph >= 0) & (ph < H_) & (pw >= 0) & (pw < W_);
        int pix = (min(max(pd, 0), D_ - 1) * H_ + min(max(ph, 0), H_ - 1)) * W_
                  + min(max(pw, 0), W_ - 1);
#pragma unroll
        for (int cc = 0; cc < 6; ++cc) pv[cc] = plane[cc][pix];
    }

#pragma unroll 1
    for (;;) {
        int kn = k + 2;
        bool have_next = (kn < 27);
        // write current tap's data to LDS (masked)
#pragma unroll
        for (int cc = 0; cc < 6; ++cc) {
            u32x4 t = valid ? pv[cc] : z;
            *(u32x4*)&S[wid][lane][(cc ^ l7) * 8] = t;
        }
        // issue next tap's gathers (latency hides under MFMA below)
        bool validn = false;
        if (have_next) {
            int kd = kn / 9 - 1, kh = (kn / 3) % 3 - 1, kw = kn % 3 - 1;
            int pd = d + kd, ph = h + kh, pw = w + kw;
            validn = (pd >= 0) & (pd < D_) & (ph >= 0) & (ph < H_) & (pw >= 0) & (pw < W_);
            int pix = (min(max(pd, 0), D_ - 1) * H_ + min(max(ph, 0), H_ - 1)) * W_
                      + min(max(pw, 0), W_ - 1);
#pragma unroll
            for (int cc = 0; cc < 6; ++cc) pv[cc] = plane[cc][pix];
        }
        // A-frags + MFMA for current tap k
        const unsigned short* wk = wf + (size_t)k * 4096 + lane * 8;
        bf16x8 a[4][2];
#pragma unroll
        for (int mt = 0; mt < 4; ++mt)
#pragma unroll
            for (int ks = 0; ks < 2; ++ks)
                a[mt][ks] = *(const bf16x8*)&wk[(mt * 2 + ks) * 512];
#pragma unroll
        for (int nt = 0; nt < 4; ++nt) {
            const unsigned short* sr = &S[wid][nt * 16 + li][0];
            bf16x8 b0 = *(const bf16x8*)&sr[((0 + g) ^ l7) * 8];
            bf16x8 b1 = *(const bf16x8*)&sr[((4 + g) ^ l7) * 8];
#pragma unroll
            for (int mt = 0; mt < 4; ++mt) {
                acc[mt][nt] = __builtin_amdgcn_mfma_f32_16x16x32_bf16(a[mt][0], b0, acc[mt][nt], 0, 0, 0);
                acc[mt][nt] = __builtin_amdgcn_mfma_f32_16x16x32_bf16(a[mt][1], b1, acc[mt][nt], 0, 0, 0);
            }
        }
        if (!have_next) break;
        k = kn;
        valid = validn;
    }

    // cross-wave tap reduction through S (two 8KB phases, static indexing).
    // Barrier FIRST: staging tiles (aliased by XCH) must be dead.
    float* XCH = (float*)&S[0][0][0];
    __syncthreads();
    if (wid == 1) {
#pragma unroll
        for (int mt = 0; mt < 2; ++mt)
#pragma unroll
            for (int nt = 0; nt < 4; ++nt)
                *(f32x4*)(XCH + (mt * 4 + nt) * 256 + lane * 4) = acc[mt][nt];
    }
    __syncthreads();
    if (wid == 0) {
#pragma unroll
        for (int mt = 0; mt < 2; ++mt)
#pragma unroll
            for (int nt = 0; nt < 4; ++nt)
                acc[mt][nt] += *(f32x4*)(XCH + (mt * 4 + nt) * 256 + lane * 4);
    }
    __syncthreads();
    if (wid == 1) {
#pragma unroll
        for (int mt = 2; mt < 4; ++mt)
#pragma unroll
            for (int nt = 0; nt < 4; ++nt)
                *(f32x4*)(XCH + ((mt - 2) * 4 + nt) * 256 + lane * 4) = acc[mt][nt];
    }
    __syncthreads();
    if (wid == 1) return;
#pragma unroll
    for (int mt = 2; mt < 4; ++mt)
#pragma unroll
        for (int nt = 0; nt < 4; ++nt)
            acc[mt][nt] += *(f32x4*)(XCH + ((mt - 2) * 4 + nt) * 256 + lane * 4);

    int s0 = base - b * DHW_;
#pragma unroll
    for (int mt = 0; mt < 4; ++mt) {
#pragma unroll
        for (int r = 0; r < 4; ++r) {
            int oc = mt * 16 + 4 * g + r;
            if (oc < OFFC_) {
                float bb = bo[oc];
#pragma unroll
                for (int nt = 0; nt < 4; ++nt) {
                    size_t addr = ((size_t)b * OFFC_ + oc) * DHW_ + (s0 + nt * 16 + li);
                    off[addr] = acc[mt][nt][r] + bb;
                }
            }
        }
    }
}

// ---------------- deformable conv (bilinear HW, integer D) via MFMA ----------------
template <int LEAKY, int RESID, int CLOUT>
__global__ void __launch_bounds__(128) deform_mfma(
    const unsigned short* __restrict__ scl,   // [6][NLOC][8] bf16 chunk-planes
    const float* __restrict__ off,            // [B][54][DHW] fp32
    const unsigned short* __restrict__ wf,    // frag-packed, MT=3
    const float* __restrict__ bias,           // [48]
    const float* __restrict__ resid,          // [B][48][DHW] fp32 (RESID)
    float* __restrict__ dstf,                 // [B][48][DHW] fp32 (!CLOUT)
    unsigned short* __restrict__ dstcl) {     // [6][NLOC][8] bf16 (CLOUT)
    __shared__ unsigned short S[2][64][64];
    int tid = threadIdx.x, wid = tid >> 6, lane = tid & 63;
    int base = xcd_swizzle(blockIdx.x, gridDim.x) * 64;
    int loc = base + lane;
    int b = loc / DHW_;
    int sp = loc - b * DHW_;
    int w = sp % W_; int t1 = sp / W_;
    int h = t1 % H_; int d = t1 / H_;
    int g = lane >> 4, li = lane & 15, l7 = lane & 7;

    u32x4 z = {0, 0, 0, 0};
    *(u32x4*)&S[wid][lane][(6 ^ l7) * 8] = z;
    *(u32x4*)&S[wid][lane][(7 ^ l7) * 8] = z;

    f32x4 acc[3][4];
#pragma unroll
    for (int mt = 0; mt < 3; ++mt)
#pragma unroll
        for (int nt = 0; nt < 4; ++nt) acc[mt][nt] = (f32x4){0.f, 0.f, 0.f, 0.f};

    const u32x4* plane[6];
#pragma unroll
    for (int q = 0; q < 6; ++q)
        plane[q] = (const u32x4*)(scl + ((size_t)q * NLOC_ + (size_t)b * DHW_) * 8);
    const float* ob = off + (size_t)b * (OFFC_ * DHW_) + sp;

    // ---- pipeline prologue: tap k0 (offsets, meta, gathers) + offsets k0+2 ----
    int k = wid;
    u32x4 st[6][4];
    f32x2 wp0, wp1, wp2, wp3;
    float odh_n = 0.f, odw_n = 0.f;
    {
        float odh = ob[(size_t)(2 * k + 0) * DHW_];
        float odw = ob[(size_t)(2 * k + 1) * DHW_];
        int kd = k / 9 - 1, kh = (k / 3) % 3 - 1, kw = k % 3 - 1;
        int pd = d + kd;
        bool vd = (pd >= 0) & (pd < D_);
        int pdc = min(max(pd, 0), D_ - 1);
        float phf = (float)(h + kh) + odh;
        float pwf = (float)(w + kw) + odw;
        float h0f = floorf(phf), w0f = floorf(pwf);
        float th = phf - h0f, tw = pwf - w0f;
        int h0 = (int)h0f, w0 = (int)w0f;
        int pix[4];
        f32x4 cw;
#pragma unroll
        for (int dh = 0; dh < 2; ++dh) {
            int hh = h0 + dh;
            bool vh = vd & (hh >= 0) & (hh < H_);
            int hhc = min(max(hh, 0), H_ - 1);
            float whv = dh ? th : 1.0f - th;
#pragma unroll
            for (int dw = 0; dw < 2; ++dw) {
                int ww = w0 + dw;
                bool v = vh & (ww >= 0) & (ww < W_);
                int wwc = min(max(ww, 0), W_ - 1);
                float wwt = dw ? tw : 1.0f - tw;
                pix[dh * 2 + dw] = (pdc * H_ + hhc) * W_ + wwc;
                cw[dh * 2 + dw] = v ? whv * wwt : 0.0f;
            }
        }
        wp0 = (f32x2){cw[0], cw[0]}; wp1 = (f32x2){cw[1], cw[1]};
        wp2 = (f32x2){cw[2], cw[2]}; wp3 = (f32x2){cw[3], cw[3]};
#pragma unroll
        for (int cc = 0; cc < 6; ++cc)
#pragma unroll
            for (int j = 0; j < 4; ++j) st[cc][j] = plane[cc][pix[j]];
        if (k + 2 < 27) {
            odh_n = ob[(size_t)(2 * (k + 2) + 0) * DHW_];
            odw_n = ob[(size_t)(2 * (k + 2) + 1) * DHW_];
        }
    }

#pragma unroll 1
    for (;;) {
        int kn = k + 2;
        bool have_next = (kn < 27);
        // prefetch offsets two taps ahead (consumed next iteration's meta)
        float odh_nn = 0.f, odw_nn = 0.f;
        if (kn + 2 < 27) {
            odh_nn = ob[(size_t)(2 * (kn + 2) + 0) * DHW_];
            odw_nn = ob[(size_t)(2 * (kn + 2) + 1) * DHW_];
        }
        // interp current tap (consumes st) -> LDS
#pragma unroll
        for (int cc = 0; cc < 6; ++cc) {
            u32x4 pvv = interp4_pk(st[cc][0], st[cc][1], st[cc][2], st[cc][3],
                                   wp0, wp1, wp2, wp3);
            *(u32x4*)&S[wid][lane][(cc ^ l7) * 8] = pvv;
        }
        // meta + issue gathers for NEXT tap (offsets already resident)
        if (have_next) {
            int kd = kn / 9 - 1, kh = (kn / 3) % 3 - 1, kw = kn % 3 - 1;
            int pd = d + kd;
            bool vd = (pd >= 0) & (pd < D_);
            int pdc = min(max(pd, 0), D_ - 1);
            float phf = (float)(h + kh) + odh_n;
            float pwf = (float)(w + kw) + odw_n;
            float h0f = floorf(phf), w0f = floorf(pwf);
            float th = phf - h0f, tw = pwf - w0f;
            int h0 = (int)h0f, w0 = (int)w0f;
            int pix[4];
            f32x4 cw;
#pragma unroll
            for (int dh = 0; dh < 2; ++dh) {
                int hh = h0 + dh;
                bool vh = vd & (hh >= 0) & (hh < H_);
                int hhc = min(max(hh, 0), H_ - 1);
                float whv = dh ? th : 1.0f - th;
#pragma unroll
                for (int dw = 0; dw < 2; ++dw) {
                    int ww = w0 + dw;
                    bool v = vh & (ww >= 0) & (ww < W_);
                    int wwc = min(max(ww, 0), W_ - 1);
                    float wwt = dw ? tw : 1.0f - tw;
                    pix[dh * 2 + dw] = (pdc * H_ + hhc) * W_ + wwc;
                    cw[dh * 2 + dw] = v ? whv * wwt : 0.0f;
                }
            }
            wp0 = (f32x2){cw[0], cw[0]}; wp1 = (f32x2){cw[1], cw[1]};
            wp2 = (f32x2){cw[2], cw[2]}; wp3 = (f32x2){cw[3], cw[3]};
#pragma unroll
            for (int cc = 0; cc < 6; ++cc)
#pragma unroll
                for (int j = 0; j < 4; ++j) st[cc][j] = plane[cc][pix[j]];
        }
        // A-frags + MFMA for current tap k (gathers for kn fly underneath)
        const unsigned short* wk = wf + (size_t)k * 3072 + lane * 8;
        bf16x8 a[3][2];
#pragma unroll
        for (int mt = 0; mt < 3; ++mt)
#pragma unroll
            for (int ks = 0; ks < 2; ++ks)
                a[mt][ks] = *(const bf16x8*)&wk[(mt * 2 + ks) * 512];
#pragma unroll
        for (int nt = 0; nt < 4; ++nt) {
            const unsigned short* sr = &S[wid][nt * 16 + li][0];
            bf16x8 b0 = *(const bf16x8*)&sr[((0 + g) ^ l7) * 8];
            bf16x8 b1 = *(const bf16x8*)&sr[((4 + g) ^ l7) * 8];
#pragma unroll
            for (int mt = 0; mt < 3; ++mt) {
                acc[mt][nt] = __builtin_amdgcn_mfma_f32_16x16x32_bf16(a[mt][0], b0, acc[mt][nt], 0, 0, 0);
                acc[mt][nt] = __builtin_amdgcn_mfma_f32_16x16x32_bf16(a[mt][1], b1, acc[mt][nt], 0, 0, 0);
            }
        }
        if (!have_next) break;
        k = kn;
        odh_n = odh_nn;
        odw_n = odw_nn;
    }

    // cross-wave tap reduction through S[1] (keeps S[0] free for CLOUT
    // transpose). Barrier first: no wave may still be using its staging tile.
    float* XCH = (float*)&S[1][0][0];   // 8KB = 8 groups of 1KB
    __syncthreads();
    if (wid == 1) {
#pragma unroll
        for (int mt = 0; mt < 2; ++mt)
#pragma unroll
            for (int nt = 0; nt < 4; ++nt)
                *(f32x4*)(XCH + (mt * 4 + nt) * 256 + lane * 4) = acc[mt][nt];
    }
    __syncthreads();
    if (wid == 0) {
#pragma unroll
        for (int mt = 0; mt < 2; ++mt)
#pragma unroll
            for (int nt = 0; nt < 4; ++nt)
                acc[mt][nt] += *(f32x4*)(XCH + (mt * 4 + nt) * 256 + lane * 4);
    }
    __syncthreads();
    if (wid == 1) {
#pragma unroll
        for (int nt = 0; nt < 4; ++nt)
            *(f32x4*)(XCH + nt * 256 + lane * 4) = acc[2][nt];
    }
    __syncthreads();
    if (wid == 1) return;
#pragma unroll
    for (int nt = 0; nt < 4; ++nt)
        acc[2][nt] += *(f32x4*)(XCH + nt * 256 + lane * 4);

    if (CLOUT) {
        // Transpose D-tile through wave0's (now free) S[0] tile, then write
        // bf16 chunk-planes: 16B/lane dense per plane, fully coalesced.
        unsigned short* Sb = &S[0][0][0];   // row stride 64 u16 = 128 B
#pragma unroll
        for (int mt = 0; mt < 3; ++mt) {
#pragma unroll
            for (int nt = 0; nt < 4; ++nt) {
                float v[4];
#pragma unroll
                for (int r = 0; r < 4; ++r) {
                    int oc = mt * 16 + 4 * g + r;
                    float t = acc[mt][nt][r] + bias[oc];
                    if (LEAKY) t = (t >= 0.f) ? t : 0.1f * t;
                    v[r] = t;
                }
                int row = nt * 16 + li;
                int colb = (mt * 32 + 8 * g) ^ ((li & 7) << 4);
                u32x2 pp = {cvt_pk_bf16(v[0], v[1]), cvt_pk_bf16(v[2], v[3])};
                *(u32x2*)((char*)(Sb + (size_t)row * 64) + colb) = pp;
            }
        }
        unsigned short* myrow = Sb + (size_t)lane * 64;
#pragma unroll
        for (int s = 0; s < 6; ++s) {
            u32x4 c = *(u32x4*)((char*)myrow + ((s * 16) ^ ((lane & 7) << 4)));
            *(u32x4*)(dstcl + ((size_t)s * NLOC_ + loc) * 8) = c;
        }
    } else {
        int s0 = base - b * DHW_;
#pragma unroll
        for (int mt = 0; mt < 3; ++mt) {
#pragma unroll
            for (int r = 0; r < 4; ++r) {
                int oc = mt * 16 + 4 * g + r;
                float bb = bias[oc];
#pragma unroll
                for (int nt = 0; nt < 4; ++nt) {
                    size_t addr = ((size_t)b * C_ + oc) * DHW_ + (s0 + nt * 16 + li);
                    float v = acc[mt][nt][r] + bb;
                    if (LEAKY) v = (v >= 0.0f) ? v : 0.1f * v;
                    if (RESID) v += resid[addr];
                    dstf[addr] = v;
                }
            }
        }
    }
}

extern "C" void kernel_launch(void* const* d_in, const int* in_sizes, int n_in,
                              void* d_out, int out_size, void* d_ws, size_t ws_size,
                              hipStream_t stream) {
    const float* x      = (const float*)d_in[0];
    const float* w_off0 = (const float*)d_in[1];
    const float* b_off0 = (const float*)d_in[2];
    const float* w0     = (const float*)d_in[3];
    const float* b0     = (const float*)d_in[4];
    const float* w_off1 = (const float*)d_in[5];
    const float* b_off1 = (const float*)d_in[6];
    const float* w1     = (const float*)d_in[7];
    const float* b1     = (const float*)d_in[8];
    float* out = (float*)d_out;

    // ws: off (54*NLOC f32) | xcl (48*NLOC bf16) | hcl (48*NLOC bf16) | wf_off | wf_conv
    float* off_buf = (float*)d_ws;
    unsigned short* xcl = (unsigned short*)(off_buf + (size_t)OFFC_ * NLOC_);
    unsigned short* hcl = xcl + (size_t)NLOC_ * 48;
    unsigned short* wf_off  = hcl + (size_t)NLOC_ * 48;
    unsigned short* wf_conv = wf_off + 27 * 4 * 1024;

    dim3 blk128(128), blk256(256);
    int nblk = NLOC_ / 64;    // 2352 (divisible by 8)

    to_cl_kernel<<<NLOC_ / 256, blk256, 0, stream>>>(x, xcl);

    // --- layer 0 ---
    repack_frag_kernel<<<(27 * 4 * 1024 + 255) / 256, blk256, 0, stream>>>(w_off0, wf_off, OFFC_, 4);
    repack_frag_kernel<<<(27 * 3 * 1024 + 255) / 256, blk256, 0, stream>>>(w0, wf_conv, C_, 3);
    offconv_mfma<<<nblk, blk128, 0, stream>>>(xcl, wf_off, b_off0, off_buf);
    deform_mfma<1, 0, 1><<<nblk, blk128, 0, stream>>>(xcl, off_buf, wf_conv, b0, nullptr, nullptr, hcl);

    // --- layer 1 ---
    repack_frag_kernel<<<(27 * 4 * 1024 + 255) / 256, blk256, 0, stream>>>(w_off1, wf_off, OFFC_, 4);
    repack_frag_kernel<<<(27 * 3 * 1024 + 255) / 256, blk256, 0, stream>>>(w1, wf_conv, C_, 3);
    offconv_mfma<<<nblk, blk128, 0, stream>>>(hcl, wf_off, b_off1, off_buf);
    deform_mfma<0, 1, 0><<<nblk, blk128, 0, stream>>>(hcl, off_buf, wf_conv, b1, x, out, nullptr);
}

// Round 14
// 293.124 us; speedup vs baseline: 1.1547x; 1.1547x over previous
//
#include <hip/hip_runtime.h>
#include <hip/hip_bf16.h>

// (B, nf, D, H, W) = (4, 48, 12, 56, 56), fp32 in/out, bf16 MFMA internally.
// Sampled tensors: SIX bf16 chunk-planes [6][NLOC][8ch] (16B/pixel stride).
// Round 14: FUSED layer kernel. off[b,:,d,h,w] feeds ONLY the deform output
// at the same location, so each block computes its 64 locations' 54 offset
// channels (phase A = round-8 offconv, MFMA-heavy), stores them in an LDS
// table, barriers, then runs the round-8 deform loop reading offsets from
// LDS (phase B, gather/VALU-heavy). Kills the off global round-trip, two
// launches, and lets neighbor blocks overlap A/B pipes on a CU. Plus a
// wave-uniform __all skip of depth-invalid tap groups.
constexpr int B_ = 4, C_ = 48, D_ = 12, H_ = 56, W_ = 56;
constexpr int DHW_ = D_ * H_ * W_;        // 37632
constexpr int NLOC_ = B_ * DHW_;          // 150528 -> 2352 blocks of 128
constexpr int OFFC_ = 54;                 // 27 taps x 2 (dh, dw)
constexpr int NXCD_ = 8;

typedef short bf16x8 __attribute__((ext_vector_type(8)));
typedef float f32x4  __attribute__((ext_vector_type(4)));
typedef float f32x2  __attribute__((ext_vector_type(2)));
typedef unsigned int u32x4 __attribute__((ext_vector_type(4)));
typedef unsigned int u32x2 __attribute__((ext_vector_type(2)));

__device__ __forceinline__ int xcd_swizzle(int bid, int nwg) {
    int xcd = bid % NXCD_, lid = bid / NXCD_;
    int q = nwg / NXCD_, r = nwg % NXCD_;
    return (xcd < r ? xcd * (q + 1) : r * (q + 1) + (xcd - r) * q) + lid;
}

__device__ __forceinline__ unsigned int f2bf_u(float f) {
    __hip_bfloat16 h = __float2bfloat16(f);
    return (unsigned int)__builtin_bit_cast(unsigned short, h);
}
__device__ __forceinline__ float bflo(unsigned int pv) {
    return __builtin_bit_cast(float, pv << 16);
}
__device__ __forceinline__ float bfhi(unsigned int pv) {
    return __builtin_bit_cast(float, pv & 0xffff0000u);
}

// 4-corner bilinear on a 16B chunk (8 bf16 channels), fp32 math, bf16 out.
__device__ __forceinline__ u32x4 interp4(u32x4 c00, u32x4 c01, u32x4 c10, u32x4 c11,
                                         f32x4 cw) {
    u32x4 pv;
#pragma unroll
    for (int u = 0; u < 4; ++u) {
        float lo = cw[0] * bflo(c00[u]);
        lo = fmaf(cw[1], bflo(c01[u]), lo);
        lo = fmaf(cw[2], bflo(c10[u]), lo);
        lo = fmaf(cw[3], bflo(c11[u]), lo);
        float hi = cw[0] * bfhi(c00[u]);
        hi = fmaf(cw[1], bfhi(c01[u]), hi);
        hi = fmaf(cw[2], bfhi(c10[u]), hi);
        hi = fmaf(cw[3], bfhi(c11[u]), hi);
        pv[u] = f2bf_u(lo) | (f2bf_u(hi) << 16);
    }
    return pv;
}

// Pack weights into MFMA A-fragment order (bf16):
// wf[k][mt][ks][lane][i] = W[oc=mt*16+(lane&15)][c=ks*32+8*(lane>>4)+i][tap k]
__global__ void __launch_bounds__(256) repack_frag_kernel(
    const float* __restrict__ w, unsigned short* __restrict__ wf, int OC, int MT) {
    int t = blockIdx.x * 256 + threadIdx.x;
    int total = 27 * MT * 1024;
    if (t >= total) return;
    int i    = t & 7;
    int lane = (t >> 3) & 63;
    int ks   = (t >> 9) & 1;
    int mt   = (t >> 10) % MT;
    int k    = t / (MT << 10);
    int oc = mt * 16 + (lane & 15);
    int c  = ks * 32 + 8 * (lane >> 4) + i;
    float v = (oc < OC && c < 48) ? w[((size_t)oc * 48 + c) * 27 + k] : 0.0f;
    wf[t] = (unsigned short)f2bf_u(v);
}

// fp32 [B][48][DHW] -> bf16 chunk-planes [6][NLOC][8].
__global__ void __launch_bounds__(256) to_cl_kernel(const float* __restrict__ x,
                                                    unsigned short* __restrict__ xcl) {
    int loc = blockIdx.x * 256 + threadIdx.x;
    int b = loc / DHW_, s = loc - b * DHW_;
    const float* xp = x + (size_t)b * (C_ * DHW_) + s;
#pragma unroll
    for (int q = 0; q < 6; ++q) {
        float v[8];
#pragma unroll
        for (int u = 0; u < 8; ++u) v[u] = xp[(size_t)(q * 8 + u) * DHW_];
        u32x4 o;
#pragma unroll
        for (int u = 0; u < 4; ++u)
            o[u] = f2bf_u(v[2 * u]) | (f2bf_u(v[2 * u + 1]) << 16);
        *(u32x4*)(xcl + ((size_t)q * NLOC_ + loc) * 8) = o;   // 16B/lane dense
    }
}

// ---------------- fused layer: offconv (phase A) + deform (phase B) -------------
// Block = 128 = 2 waves sharing 64 locations; wave w does taps k === w (mod 2)
// in both phases. Offsets handed A->B through the OFT LDS table.
template <int LEAKY, int RESID, int CLOUT>
__global__ void __launch_bounds__(128) fused_layer(
    const unsigned short* __restrict__ scl,   // [6][NLOC][8] bf16 chunk-planes
    const unsigned short* __restrict__ wfo,   // offconv frag weights, MT=4
    const float* __restrict__ bo,             // [54]
    const unsigned short* __restrict__ wfc,   // deform frag weights, MT=3
    const float* __restrict__ bias,           // [48]
    const float* __restrict__ resid,          // [B][48][DHW] fp32 (RESID)
    float* __restrict__ dstf,                 // [B][48][DHW] fp32 (!CLOUT)
    unsigned short* __restrict__ dstcl) {     // [6][NLOC][8] bf16 (CLOUT)
    __shared__ unsigned short S[2][64][64];        // 16KB staging + exchange
    __shared__ __align__(16) float OFT[64][58];    // 14.8KB offsets (stride 58: bank-safe)
    int tid = threadIdx.x, wid = tid >> 6, lane = tid & 63;
    int base = xcd_swizzle(blockIdx.x, gridDim.x) * 64;
    int loc = base + lane;
    int b = loc / DHW_;
    int sp = loc - b * DHW_;
    int w = sp % W_; int t1 = sp / W_;
    int h = t1 % H_; int d = t1 / H_;
    int g = lane >> 4, li = lane & 15, l7 = lane & 7;

    u32x4 z = {0, 0, 0, 0};
    *(u32x4*)&S[wid][lane][(6 ^ l7) * 8] = z;   // K-pad channels 48..63
    *(u32x4*)&S[wid][lane][(7 ^ l7) * 8] = z;

    const u32x4* plane[6];
#pragma unroll
    for (int q = 0; q < 6; ++q)
        plane[q] = (const u32x4*)(scl + ((size_t)q * NLOC_ + (size_t)b * DHW_) * 8);

    // ================= phase A: offset conv (54 channels) =================
    {
        f32x4 acc[4][4];
#pragma unroll
        for (int mt = 0; mt < 4; ++mt)
#pragma unroll
            for (int nt = 0; nt < 4; ++nt) acc[mt][nt] = (f32x4){0.f, 0.f, 0.f, 0.f};

#pragma unroll 1
        for (int i = 0; i < 14; ++i) {
            int k = wid + 2 * i;
            if (k >= 27) break;
            int kd = k / 9 - 1, kh = (k / 3) % 3 - 1, kw = k % 3 - 1;
            int pd = d + kd, ph = h + kh, pw = w + kw;
            bool valid = (pd >= 0) & (pd < D_) & (ph >= 0) & (ph < H_) &
                         (pw >= 0) & (pw < W_);
            if (!__any((int)valid)) continue;   // whole tap contributes zero
            int pdc = min(max(pd, 0), D_ - 1);
            int phc = min(max(ph, 0), H_ - 1);
            int pwc = min(max(pw, 0), W_ - 1);
            int pix = (pdc * H_ + phc) * W_ + pwc;
            u32x4 pv[6];
#pragma unroll
            for (int cc = 0; cc < 6; ++cc) pv[cc] = plane[cc][pix];   // coalesced
#pragma unroll
            for (int cc = 0; cc < 6; ++cc) {
                if (!valid) pv[cc] = z;
                *(u32x4*)&S[wid][lane][(cc ^ l7) * 8] = pv[cc];
            }
            const unsigned short* wk = wfo + (size_t)k * 4096 + lane * 8;
            bf16x8 a[4][2];
#pragma unroll
            for (int mt = 0; mt < 4; ++mt)
#pragma unroll
                for (int ks = 0; ks < 2; ++ks)
                    a[mt][ks] = *(const bf16x8*)&wk[(mt * 2 + ks) * 512];
#pragma unroll
            for (int nt = 0; nt < 4; ++nt) {
                const unsigned short* sr = &S[wid][nt * 16 + li][0];
                bf16x8 b0 = *(const bf16x8*)&sr[((0 + g) ^ l7) * 8];
                bf16x8 b1 = *(const bf16x8*)&sr[((4 + g) ^ l7) * 8];
#pragma unroll
                for (int mt = 0; mt < 4; ++mt) {
                    acc[mt][nt] = __builtin_amdgcn_mfma_f32_16x16x32_bf16(a[mt][0], b0, acc[mt][nt], 0, 0, 0);
                    acc[mt][nt] = __builtin_amdgcn_mfma_f32_16x16x32_bf16(a[mt][1], b1, acc[mt][nt], 0, 0, 0);
                }
            }
        }

        // cross-wave reduction through S (two 8KB phases). Barrier FIRST:
        // staging tiles (aliased by XCH) must be dead before the writes.
        float* XCH = (float*)&S[0][0][0];
        __syncthreads();
        if (wid == 1) {
#pragma unroll
            for (int mt = 0; mt < 2; ++mt)
#pragma unroll
                for (int nt = 0; nt < 4; ++nt)
                    *(f32x4*)(XCH + (mt * 4 + nt) * 256 + lane * 4) = acc[mt][nt];
        }
        __syncthreads();
        if (wid == 0) {
#pragma unroll
            for (int mt = 0; mt < 2; ++mt)
#pragma unroll
                for (int nt = 0; nt < 4; ++nt)
                    acc[mt][nt] += *(f32x4*)(XCH + (mt * 4 + nt) * 256 + lane * 4);
        }
        __syncthreads();
        if (wid == 1) {
#pragma unroll
            for (int mt = 2; mt < 4; ++mt)
#pragma unroll
                for (int nt = 0; nt < 4; ++nt)
                    *(f32x4*)(XCH + ((mt - 2) * 4 + nt) * 256 + lane * 4) = acc[mt][nt];
        }
        __syncthreads();
        if (wid == 0) {
#pragma unroll
            for (int mt = 2; mt < 4; ++mt)
#pragma unroll
                for (int nt = 0; nt < 4; ++nt)
                    acc[mt][nt] += *(f32x4*)(XCH + ((mt - 2) * 4 + nt) * 256 + lane * 4);
            // write the block's offsets (with bias) into the OFT table:
            // OFT[loc_in_block][oc], oc pairs -> 8B stores, 8B aligned.
#pragma unroll
            for (int mt = 0; mt < 4; ++mt)
#pragma unroll
                for (int nt = 0; nt < 4; ++nt)
#pragma unroll
                    for (int rp = 0; rp < 2; ++rp) {
                        int oc = mt * 16 + 4 * g + 2 * rp;
                        if (oc < OFFC_) {
                            f32x2 v = {acc[mt][nt][2 * rp] + bo[oc],
                                       acc[mt][nt][2 * rp + 1] + bo[oc + 1]};
                            *(f32x2*)&OFT[nt * 16 + li][oc] = v;
                        }
                    }
        }
        __syncthreads();   // OFT visible to all; exchange traffic fully drained
    }

    // re-init K-pad slots (phase A exchange clobbered S[0]; cheap to do both)
    *(u32x4*)&S[wid][lane][(6 ^ l7) * 8] = z;
    *(u32x4*)&S[wid][lane][(7 ^ l7) * 8] = z;

    // ================= phase B: deformable conv (48 channels) =================
    f32x4 acc[3][4];
#pragma unroll
    for (int mt = 0; mt < 3; ++mt)
#pragma unroll
        for (int nt = 0; nt < 4; ++nt) acc[mt][nt] = (f32x4){0.f, 0.f, 0.f, 0.f};

#pragma unroll 1
    for (int i = 0; i < 14; ++i) {
        int k = wid + 2 * i;
        if (k >= 27) break;
        int kd = k / 9 - 1, kh = (k / 3) % 3 - 1, kw = k % 3 - 1;
        int pd = d + kd;
        bool vd = (pd >= 0) & (pd < D_);
        if (!__any((int)vd)) continue;   // depth-invalid tap group: contributes 0
        int pdc = min(max(pd, 0), D_ - 1);

        f32x2 od = *(const f32x2*)&OFT[lane][2 * k];
        float phf = (float)(h + kh) + od.x;
        float pwf = (float)(w + kw) + od.y;
        float h0f = floorf(phf), w0f = floorf(pwf);
        float th = phf - h0f, tw = pwf - w0f;
        int h0 = (int)h0f, w0 = (int)w0f;

        int pix[4];
        f32x4 cw;
#pragma unroll
        for (int dh = 0; dh < 2; ++dh) {
            int hh = h0 + dh;
            bool vh = vd & (hh >= 0) & (hh < H_);
            int hhc = min(max(hh, 0), H_ - 1);
            float wh = dh ? th : 1.0f - th;
#pragma unroll
            for (int dw = 0; dw < 2; ++dw) {
                int ww = w0 + dw;
                bool v = vh & (ww >= 0) & (ww < W_);
                int wwc = min(max(ww, 0), W_ - 1);
                float wwt = dw ? tw : 1.0f - tw;
                pix[dh * 2 + dw] = (pdc * H_ + hhc) * W_ + wwc;   // clamped in-bounds
                cw[dh * 2 + dw] = v ? wh * wwt : 0.0f;
            }
        }

        // two halves of 12 staged 16B gathers (3 chunk-planes x 4 corners)
#pragma unroll
        for (int half = 0; half < 2; ++half) {
            u32x4 st[3][4];
#pragma unroll
            for (int cc = 0; cc < 3; ++cc)
#pragma unroll
                for (int j = 0; j < 4; ++j)
                    st[cc][j] = plane[half * 3 + cc][pix[j]];
#pragma unroll
            for (int cc = 0; cc < 3; ++cc) {
                u32x4 pv = interp4(st[cc][0], st[cc][1], st[cc][2], st[cc][3], cw);
                *(u32x4*)&S[wid][lane][((half * 3 + cc) ^ l7) * 8] = pv;
            }
        }

        const unsigned short* wk = wfc + (size_t)k * 3072 + lane * 8;
        bf16x8 a[3][2];
#pragma unroll
        for (int mt = 0; mt < 3; ++mt)
#pragma unroll
            for (int ks = 0; ks < 2; ++ks)
                a[mt][ks] = *(const bf16x8*)&wk[(mt * 2 + ks) * 512];
#pragma unroll
        for (int nt = 0; nt < 4; ++nt) {
            const unsigned short* sr = &S[wid][nt * 16 + li][0];
            bf16x8 b0 = *(const bf16x8*)&sr[((0 + g) ^ l7) * 8];
            bf16x8 b1 = *(const bf16x8*)&sr[((4 + g) ^ l7) * 8];
#pragma unroll
            for (int mt = 0; mt < 3; ++mt) {
                acc[mt][nt] = __builtin_amdgcn_mfma_f32_16x16x32_bf16(a[mt][0], b0, acc[mt][nt], 0, 0, 0);
                acc[mt][nt] = __builtin_amdgcn_mfma_f32_16x16x32_bf16(a[mt][1], b1, acc[mt][nt], 0, 0, 0);
            }
        }
    }

    // cross-wave tap reduction through S[1] (keeps S[0] free for CLOUT
    // transpose). Barrier first: no wave may still be using its staging tile.
    float* XCH = (float*)&S[1][0][0];   // 8KB = 8 groups of 1KB
    __syncthreads();
    if (wid == 1) {
#pragma unroll
        for (int mt = 0; mt < 2; ++mt)
#pragma unroll
            for (int nt = 0; nt < 4; ++nt)
                *(f32x4*)(XCH + (mt * 4 + nt) * 256 + lane * 4) = acc[mt][nt];
    }
    __syncthreads();
    if (wid == 0) {
#pragma unroll
        for (int mt = 0; mt < 2; ++mt)
#pragma unroll
            for (int nt = 0; nt < 4; ++nt)
                acc[mt][nt] += *(f32x4*)(XCH + (mt * 4 + nt) * 256 + lane * 4);
    }
    __syncthreads();
    if (wid == 1) {
#pragma unroll
        for (int nt = 0; nt < 4; ++nt)
            *(f32x4*)(XCH + nt * 256 + lane * 4) = acc[2][nt];
    }
    __syncthreads();
    if (wid == 1) return;
#pragma unroll
    for (int nt = 0; nt < 4; ++nt)
        acc[2][nt] += *(f32x4*)(XCH + nt * 256 + lane * 4);

    if (CLOUT) {
        // Transpose D-tile through wave0's (now free) S[0] tile, then write
        // bf16 chunk-planes: 16B/lane dense per plane, fully coalesced.
        unsigned short* Sb = &S[0][0][0];   // row stride 64 u16 = 128 B
#pragma unroll
        for (int mt = 0; mt < 3; ++mt) {
#pragma unroll
            for (int nt = 0; nt < 4; ++nt) {
                float v[4];
#pragma unroll
                for (int r = 0; r < 4; ++r) {
                    int oc = mt * 16 + 4 * g + r;
                    float t = acc[mt][nt][r] + bias[oc];
                    if (LEAKY) t = (t >= 0.f) ? t : 0.1f * t;
                    v[r] = t;
                }
                int row = nt * 16 + li;
                int colb = (mt * 32 + 8 * g) ^ ((li & 7) << 4);
                u32x2 pp = {f2bf_u(v[0]) | (f2bf_u(v[1]) << 16),
                            f2bf_u(v[2]) | (f2bf_u(v[3]) << 16)};
                *(u32x2*)((char*)(Sb + (size_t)row * 64) + colb) = pp;
            }
        }
        unsigned short* myrow = Sb + (size_t)lane * 64;
#pragma unroll
        for (int s = 0; s < 6; ++s) {
            u32x4 c = *(u32x4*)((char*)myrow + ((s * 16) ^ ((lane & 7) << 4)));
            *(u32x4*)(dstcl + ((size_t)s * NLOC_ + loc) * 8) = c;
        }
    } else {
        int s0 = base - b * DHW_;
#pragma unroll
        for (int mt = 0; mt < 3; ++mt) {
#pragma unroll
            for (int r = 0; r < 4; ++r) {
                int oc = mt * 16 + 4 * g + r;
                float bb = bias[oc];
#pragma unroll
                for (int nt = 0; nt < 4; ++nt) {
                    size_t addr = ((size_t)b * C_ + oc) * DHW_ + (s0 + nt * 16 + li);
                    float v = acc[mt][nt][r] + bb;
                    if (LEAKY) v = (v >= 0.0f) ? v : 0.1f * v;
                    if (RESID) v += resid[addr];
                    dstf[addr] = v;
                }
            }
        }
    }
}

extern "C" void kernel_launch(void* const* d_in, const int* in_sizes, int n_in,
                              void* d_out, int out_size, void* d_ws, size_t ws_size,
                              hipStream_t stream) {
    const float* x      = (const float*)d_in[0];
    const float* w_off0 = (const float*)d_in[1];
    const float* b_off0 = (const float*)d_in[2];
    const float* w0     = (const float*)d_in[3];
    const float* b0     = (const float*)d_in[4];
    const float* w_off1 = (const float*)d_in[5];
    const float* b_off1 = (const float*)d_in[6];
    const float* w1     = (const float*)d_in[7];
    const float* b1     = (const float*)d_in[8];
    float* out = (float*)d_out;

    // ws: xcl (48*NLOC bf16) | hcl (48*NLOC bf16) | wf_off | wf_conv
    unsigned short* xcl = (unsigned short*)d_ws;
    unsigned short* hcl = xcl + (size_t)NLOC_ * 48;
    unsigned short* wf_off  = hcl + (size_t)NLOC_ * 48;
    unsigned short* wf_conv = wf_off + 27 * 4 * 1024;

    dim3 blk128(128), blk256(256);
    int nblk = NLOC_ / 64;    // 2352 (divisible by 8)

    to_cl_kernel<<<NLOC_ / 256, blk256, 0, stream>>>(x, xcl);

    // --- layer 0 (fused offconv+deform, channels-last bf16 out) ---
    repack_frag_kernel<<<(27 * 4 * 1024 + 255) / 256, blk256, 0, stream>>>(w_off0, wf_off, OFFC_, 4);
    repack_frag_kernel<<<(27 * 3 * 1024 + 255) / 256, blk256, 0, stream>>>(w0, wf_conv, C_, 3);
    fused_layer<1, 0, 1><<<nblk, blk128, 0, stream>>>(xcl, wf_off, b_off0, wf_conv, b0,
                                                      nullptr, nullptr, hcl);

    // --- layer 1 (fused, fp32 out + residual) ---
    repack_frag_kernel<<<(27 * 4 * 1024 + 255) / 256, blk256, 0, stream>>>(w_off1, wf_off, OFFC_, 4);
    repack_frag_kernel<<<(27 * 3 * 1024 + 255) / 256, blk256, 0, stream>>>(w1, wf_conv, C_, 3);
    fused_layer<0, 1, 0><<<nblk, blk128, 0, stream>>>(hcl, wf_off, b_off1, wf_conv, b1,
                                                      x, out, nullptr);
}

// Round 15
// 283.609 us; speedup vs baseline: 1.1934x; 1.0336x over previous
//
#include <hip/hip_runtime.h>
#include <hip/hip_bf16.h>

// (B, nf, D, H, W) = (4, 48, 12, 56, 56), fp32 in/out, bf16 MFMA internally.
// Sampled tensors: SIX bf16 chunk-planes [6][NLOC][8ch] (16B/pixel stride).
// Round 15: round-14 fused layer (offconv phase A -> LDS offset table ->
// deform phase B) + packed-f32 interp (round 10, v_pk_fma_f32 + cvt_pk)
// + OFT stored as packed bf16 pairs (7.4KB instead of 14.8KB -> LDS 23.3KB,
// 6 blocks/CU ceiling instead of 5; stride 29 dwords = conflict-free).
constexpr int B_ = 4, C_ = 48, D_ = 12, H_ = 56, W_ = 56;
constexpr int DHW_ = D_ * H_ * W_;        // 37632
constexpr int NLOC_ = B_ * DHW_;          // 150528 -> 2352 blocks of 128
constexpr int OFFC_ = 54;                 // 27 taps x 2 (dh, dw)
constexpr int NXCD_ = 8;

typedef short bf16x8 __attribute__((ext_vector_type(8)));
typedef float f32x4  __attribute__((ext_vector_type(4)));
typedef float f32x2  __attribute__((ext_vector_type(2)));
typedef unsigned int u32x4 __attribute__((ext_vector_type(4)));
typedef unsigned int u32x2 __attribute__((ext_vector_type(2)));

__device__ __forceinline__ int xcd_swizzle(int bid, int nwg) {
    int xcd = bid % NXCD_, lid = bid / NXCD_;
    int q = nwg / NXCD_, r = nwg % NXCD_;
    return (xcd < r ? xcd * (q + 1) : r * (q + 1) + (xcd - r) * q) + lid;
}

__device__ __forceinline__ unsigned int f2bf_u(float f) {
    __hip_bfloat16 h = __float2bfloat16(f);
    return (unsigned int)__builtin_bit_cast(unsigned short, h);
}
__device__ __forceinline__ float bflo(unsigned int pv) {
    return __builtin_bit_cast(float, pv << 16);
}
__device__ __forceinline__ float bfhi(unsigned int pv) {
    return __builtin_bit_cast(float, pv & 0xffff0000u);
}
__device__ __forceinline__ f32x2 bfpair(unsigned int pv) {
    f32x2 r;
    r.x = __builtin_bit_cast(float, pv << 16);
    r.y = __builtin_bit_cast(float, pv & 0xffff0000u);
    return r;
}
__device__ __forceinline__ f32x2 pk_mul(f32x2 a, f32x2 b) {
    f32x2 d;
    asm("v_pk_mul_f32 %0, %1, %2" : "=v"(d) : "v"(a), "v"(b));
    return d;
}
__device__ __forceinline__ f32x2 pk_fma(f32x2 a, f32x2 b, f32x2 c) {
    f32x2 d;
    asm("v_pk_fma_f32 %0, %1, %2, %3" : "=v"(d) : "v"(a), "v"(b), "v"(c));
    return d;
}
// pack {lo,hi} f32 pair -> u32 of 2 bf16 (RNE), single instruction
__device__ __forceinline__ unsigned int cvt_pk_bf16(float lo, float hi) {
    unsigned int r;
    asm("v_cvt_pk_bf16_f32 %0, %1, %2" : "=v"(r) : "v"(lo), "v"(hi));
    return r;
}

// 4-corner bilinear on a 16B chunk (8 bf16 channels), packed-f32 math.
__device__ __forceinline__ u32x4 interp4_pk(u32x4 c00, u32x4 c01, u32x4 c10, u32x4 c11,
                                            f32x2 w0, f32x2 w1, f32x2 w2, f32x2 w3) {
    u32x4 pv;
#pragma unroll
    for (int u = 0; u < 4; ++u) {
        f32x2 r = pk_mul(w0, bfpair(c00[u]));
        r = pk_fma(w1, bfpair(c01[u]), r);
        r = pk_fma(w2, bfpair(c10[u]), r);
        r = pk_fma(w3, bfpair(c11[u]), r);
        pv[u] = cvt_pk_bf16(r.x, r.y);
    }
    return pv;
}

// Pack weights into MFMA A-fragment order (bf16):
// wf[k][mt][ks][lane][i] = W[oc=mt*16+(lane&15)][c=ks*32+8*(lane>>4)+i][tap k]
__global__ void __launch_bounds__(256) repack_frag_kernel(
    const float* __restrict__ w, unsigned short* __restrict__ wf, int OC, int MT) {
    int t = blockIdx.x * 256 + threadIdx.x;
    int total = 27 * MT * 1024;
    if (t >= total) return;
    int i    = t & 7;
    int lane = (t >> 3) & 63;
    int ks   = (t >> 9) & 1;
    int mt   = (t >> 10) % MT;
    int k    = t / (MT << 10);
    int oc = mt * 16 + (lane & 15);
    int c  = ks * 32 + 8 * (lane >> 4) + i;
    float v = (oc < OC && c < 48) ? w[((size_t)oc * 48 + c) * 27 + k] : 0.0f;
    wf[t] = (unsigned short)f2bf_u(v);
}

// fp32 [B][48][DHW] -> bf16 chunk-planes [6][NLOC][8].
__global__ void __launch_bounds__(256) to_cl_kernel(const float* __restrict__ x,
                                                    unsigned short* __restrict__ xcl) {
    int loc = blockIdx.x * 256 + threadIdx.x;
    int b = loc / DHW_, s = loc - b * DHW_;
    const float* xp = x + (size_t)b * (C_ * DHW_) + s;
#pragma unroll
    for (int q = 0; q < 6; ++q) {
        float v[8];
#pragma unroll
        for (int u = 0; u < 8; ++u) v[u] = xp[(size_t)(q * 8 + u) * DHW_];
        u32x4 o;
#pragma unroll
        for (int u = 0; u < 4; ++u)
            o[u] = cvt_pk_bf16(v[2 * u], v[2 * u + 1]);
        *(u32x4*)(xcl + ((size_t)q * NLOC_ + loc) * 8) = o;   // 16B/lane dense
    }
}

// ---------------- fused layer: offconv (phase A) + deform (phase B) -------------
// Block = 128 = 2 waves sharing 64 locations; wave w does taps k === w (mod 2)
// in both phases. Offsets handed A->B through OFT (packed bf16 pairs).
template <int LEAKY, int RESID, int CLOUT>
__global__ void __launch_bounds__(128) fused_layer(
    const unsigned short* __restrict__ scl,   // [6][NLOC][8] bf16 chunk-planes
    const unsigned short* __restrict__ wfo,   // offconv frag weights, MT=4
    const float* __restrict__ bo,             // [54]
    const unsigned short* __restrict__ wfc,   // deform frag weights, MT=3
    const float* __restrict__ bias,           // [48]
    const float* __restrict__ resid,          // [B][48][DHW] fp32 (RESID)
    float* __restrict__ dstf,                 // [B][48][DHW] fp32 (!CLOUT)
    unsigned short* __restrict__ dstcl) {     // [6][NLOC][8] bf16 (CLOUT)
    __shared__ unsigned short S[2][64][64];   // 16KB staging + exchange
    __shared__ unsigned int OFT[64][29];      // 7.4KB offsets as bf16 pairs
                                              // (stride 29: gcd(29,32)=1 -> conflict-free)
    int tid = threadIdx.x, wid = tid >> 6, lane = tid & 63;
    int base = xcd_swizzle(blockIdx.x, gridDim.x) * 64;
    int loc = base + lane;
    int b = loc / DHW_;
    int sp = loc - b * DHW_;
    int w = sp % W_; int t1 = sp / W_;
    int h = t1 % H_; int d = t1 / H_;
    int g = lane >> 4, li = lane & 15, l7 = lane & 7;

    u32x4 z = {0, 0, 0, 0};
    *(u32x4*)&S[wid][lane][(6 ^ l7) * 8] = z;   // K-pad channels 48..63
    *(u32x4*)&S[wid][lane][(7 ^ l7) * 8] = z;

    const u32x4* plane[6];
#pragma unroll
    for (int q = 0; q < 6; ++q)
        plane[q] = (const u32x4*)(scl + ((size_t)q * NLOC_ + (size_t)b * DHW_) * 8);

    // ================= phase A: offset conv (54 channels) =================
    {
        f32x4 acc[4][4];
#pragma unroll
        for (int mt = 0; mt < 4; ++mt)
#pragma unroll
            for (int nt = 0; nt < 4; ++nt) acc[mt][nt] = (f32x4){0.f, 0.f, 0.f, 0.f};

#pragma unroll 1
        for (int i = 0; i < 14; ++i) {
            int k = wid + 2 * i;
            if (k >= 27) break;
            int kd = k / 9 - 1, kh = (k / 3) % 3 - 1, kw = k % 3 - 1;
            int pd = d + kd, ph = h + kh, pw = w + kw;
            bool valid = (pd >= 0) & (pd < D_) & (ph >= 0) & (ph < H_) &
                         (pw >= 0) & (pw < W_);
            if (!__any((int)valid)) continue;   // whole tap contributes zero
            int pdc = min(max(pd, 0), D_ - 1);
            int phc = min(max(ph, 0), H_ - 1);
            int pwc = min(max(pw, 0), W_ - 1);
            int pix = (pdc * H_ + phc) * W_ + pwc;
            u32x4 pv[6];
#pragma unroll
            for (int cc = 0; cc < 6; ++cc) pv[cc] = plane[cc][pix];   // coalesced
#pragma unroll
            for (int cc = 0; cc < 6; ++cc) {
                if (!valid) pv[cc] = z;
                *(u32x4*)&S[wid][lane][(cc ^ l7) * 8] = pv[cc];
            }
            const unsigned short* wk = wfo + (size_t)k * 4096 + lane * 8;
            bf16x8 a[4][2];
#pragma unroll
            for (int mt = 0; mt < 4; ++mt)
#pragma unroll
                for (int ks = 0; ks < 2; ++ks)
                    a[mt][ks] = *(const bf16x8*)&wk[(mt * 2 + ks) * 512];
#pragma unroll
            for (int nt = 0; nt < 4; ++nt) {
                const unsigned short* sr = &S[wid][nt * 16 + li][0];
                bf16x8 b0 = *(const bf16x8*)&sr[((0 + g) ^ l7) * 8];
                bf16x8 b1 = *(const bf16x8*)&sr[((4 + g) ^ l7) * 8];
#pragma unroll
                for (int mt = 0; mt < 4; ++mt) {
                    acc[mt][nt] = __builtin_amdgcn_mfma_f32_16x16x32_bf16(a[mt][0], b0, acc[mt][nt], 0, 0, 0);
                    acc[mt][nt] = __builtin_amdgcn_mfma_f32_16x16x32_bf16(a[mt][1], b1, acc[mt][nt], 0, 0, 0);
                }
            }
        }

        // cross-wave reduction through S (two 8KB phases). Barrier FIRST:
        // staging tiles (aliased by XCH) must be dead before the writes.
        float* XCH = (float*)&S[0][0][0];
        __syncthreads();
        if (wid == 1) {
#pragma unroll
            for (int mt = 0; mt < 2; ++mt)
#pragma unroll
                for (int nt = 0; nt < 4; ++nt)
                    *(f32x4*)(XCH + (mt * 4 + nt) * 256 + lane * 4) = acc[mt][nt];
        }
        __syncthreads();
        if (wid == 0) {
#pragma unroll
            for (int mt = 0; mt < 2; ++mt)
#pragma unroll
                for (int nt = 0; nt < 4; ++nt)
                    acc[mt][nt] += *(f32x4*)(XCH + (mt * 4 + nt) * 256 + lane * 4);
        }
        __syncthreads();
        if (wid == 1) {
#pragma unroll
            for (int mt = 2; mt < 4; ++mt)
#pragma unroll
                for (int nt = 0; nt < 4; ++nt)
                    *(f32x4*)(XCH + ((mt - 2) * 4 + nt) * 256 + lane * 4) = acc[mt][nt];
        }
        __syncthreads();
        if (wid == 0) {
#pragma unroll
            for (int mt = 2; mt < 4; ++mt)
#pragma unroll
                for (int nt = 0; nt < 4; ++nt)
                    acc[mt][nt] += *(f32x4*)(XCH + ((mt - 2) * 4 + nt) * 256 + lane * 4);
            // OFT[loc][k] = packed bf16 (odh, odw) with bias. oc = mt*16+4g+2rp
            // is always even; k = oc/2 = mt*8+2g+rp.
#pragma unroll
            for (int mt = 0; mt < 4; ++mt)
#pragma unroll
                for (int nt = 0; nt < 4; ++nt)
#pragma unroll
                    for (int rp = 0; rp < 2; ++rp) {
                        int oc = mt * 16 + 4 * g + 2 * rp;
                        if (oc < OFFC_) {
                            int kk = mt * 8 + 2 * g + rp;
                            OFT[nt * 16 + li][kk] =
                                cvt_pk_bf16(acc[mt][nt][2 * rp] + bo[oc],
                                            acc[mt][nt][2 * rp + 1] + bo[oc + 1]);
                        }
                    }
        }
        __syncthreads();   // OFT visible to all; exchange traffic fully drained
    }

    // re-init K-pad slots (phase A exchange clobbered S[0]; cheap to do both)
    *(u32x4*)&S[wid][lane][(6 ^ l7) * 8] = z;
    *(u32x4*)&S[wid][lane][(7 ^ l7) * 8] = z;

    // ================= phase B: deformable conv (48 channels) =================
    f32x4 acc[3][4];
#pragma unroll
    for (int mt = 0; mt < 3; ++mt)
#pragma unroll
        for (int nt = 0; nt < 4; ++nt) acc[mt][nt] = (f32x4){0.f, 0.f, 0.f, 0.f};

#pragma unroll 1
    for (int i = 0; i < 14; ++i) {
        int k = wid + 2 * i;
        if (k >= 27) break;
        int kd = k / 9 - 1, kh = (k / 3) % 3 - 1, kw = k % 3 - 1;
        int pd = d + kd;
        bool vd = (pd >= 0) & (pd < D_);
        if (!__any((int)vd)) continue;   // depth-invalid tap group: contributes 0
        int pdc = min(max(pd, 0), D_ - 1);

        unsigned int ou = OFT[lane][k];
        float odh = bflo(ou), odw = bfhi(ou);
        float phf = (float)(h + kh) + odh;
        float pwf = (float)(w + kw) + odw;
        float h0f = floorf(phf), w0f = floorf(pwf);
        float th = phf - h0f, tw = pwf - w0f;
        int h0 = (int)h0f, w0 = (int)w0f;

        int pix[4];
        f32x4 cw;
#pragma unroll
        for (int dh = 0; dh < 2; ++dh) {
            int hh = h0 + dh;
            bool vh = vd & (hh >= 0) & (hh < H_);
            int hhc = min(max(hh, 0), H_ - 1);
            float wh = dh ? th : 1.0f - th;
#pragma unroll
            for (int dw = 0; dw < 2; ++dw) {
                int ww = w0 + dw;
                bool v = vh & (ww >= 0) & (ww < W_);
                int wwc = min(max(ww, 0), W_ - 1);
                float wwt = dw ? tw : 1.0f - tw;
                pix[dh * 2 + dw] = (pdc * H_ + hhc) * W_ + wwc;   // clamped in-bounds
                cw[dh * 2 + dw] = v ? wh * wwt : 0.0f;
            }
        }
        f32x2 w0p = {cw[0], cw[0]}, w1p = {cw[1], cw[1]};
        f32x2 w2p = {cw[2], cw[2]}, w3p = {cw[3], cw[3]};

        // two halves of 12 staged 16B gathers (3 chunk-planes x 4 corners)
#pragma unroll
        for (int half = 0; half < 2; ++half) {
            u32x4 st[3][4];
#pragma unroll
            for (int cc = 0; cc < 3; ++cc)
#pragma unroll
                for (int j = 0; j < 4; ++j)
                    st[cc][j] = plane[half * 3 + cc][pix[j]];
#pragma unroll
            for (int cc = 0; cc < 3; ++cc) {
                u32x4 pv = interp4_pk(st[cc][0], st[cc][1], st[cc][2], st[cc][3],
                                      w0p, w1p, w2p, w3p);
                *(u32x4*)&S[wid][lane][((half * 3 + cc) ^ l7) * 8] = pv;
            }
        }

        const unsigned short* wk = wfc + (size_t)k * 3072 + lane * 8;
        bf16x8 a[3][2];
#pragma unroll
        for (int mt = 0; mt < 3; ++mt)
#pragma unroll
            for (int ks = 0; ks < 2; ++ks)
                a[mt][ks] = *(const bf16x8*)&wk[(mt * 2 + ks) * 512];
#pragma unroll
        for (int nt = 0; nt < 4; ++nt) {
            const unsigned short* sr = &S[wid][nt * 16 + li][0];
            bf16x8 b0 = *(const bf16x8*)&sr[((0 + g) ^ l7) * 8];
            bf16x8 b1 = *(const bf16x8*)&sr[((4 + g) ^ l7) * 8];
#pragma unroll
            for (int mt = 0; mt < 3; ++mt) {
                acc[mt][nt] = __builtin_amdgcn_mfma_f32_16x16x32_bf16(a[mt][0], b0, acc[mt][nt], 0, 0, 0);
                acc[mt][nt] = __builtin_amdgcn_mfma_f32_16x16x32_bf16(a[mt][1], b1, acc[mt][nt], 0, 0, 0);
            }
        }
    }

    // cross-wave tap reduction through S[1] (keeps S[0] free for CLOUT
    // transpose). Barrier first: no wave may still be using its staging tile.
    float* XCH = (float*)&S[1][0][0];   // 8KB = 8 groups of 1KB
    __syncthreads();
    if (wid == 1) {
#pragma unroll
        for (int mt = 0; mt < 2; ++mt)
#pragma unroll
            for (int nt = 0; nt < 4; ++nt)
                *(f32x4*)(XCH + (mt * 4 + nt) * 256 + lane * 4) = acc[mt][nt];
    }
    __syncthreads();
    if (wid == 0) {
#pragma unroll
        for (int mt = 0; mt < 2; ++mt)
#pragma unroll
            for (int nt = 0; nt < 4; ++nt)
                acc[mt][nt] += *(f32x4*)(XCH + (mt * 4 + nt) * 256 + lane * 4);
    }
    __syncthreads();
    if (wid == 1) {
#pragma unroll
        for (int nt = 0; nt < 4; ++nt)
            *(f32x4*)(XCH + nt * 256 + lane * 4) = acc[2][nt];
    }
    __syncthreads();
    if (wid == 1) return;
#pragma unroll
    for (int nt = 0; nt < 4; ++nt)
        acc[2][nt] += *(f32x4*)(XCH + nt * 256 + lane * 4);

    if (CLOUT) {
        // Transpose D-tile through wave0's (now free) S[0] tile, then write
        // bf16 chunk-planes: 16B/lane dense per plane, fully coalesced.
        unsigned short* Sb = &S[0][0][0];   // row stride 64 u16 = 128 B
#pragma unroll
        for (int mt = 0; mt < 3; ++mt) {
#pragma unroll
            for (int nt = 0; nt < 4; ++nt) {
                float v[4];
#pragma unroll
                for (int r = 0; r < 4; ++r) {
                    int oc = mt * 16 + 4 * g + r;
                    float t = acc[mt][nt][r] + bias[oc];
                    if (LEAKY) t = (t >= 0.f) ? t : 0.1f * t;
                    v[r] = t;
                }
                int row = nt * 16 + li;
                int colb = (mt * 32 + 8 * g) ^ ((li & 7) << 4);
                u32x2 pp = {cvt_pk_bf16(v[0], v[1]), cvt_pk_bf16(v[2], v[3])};
                *(u32x2*)((char*)(Sb + (size_t)row * 64) + colb) = pp;
            }
        }
        unsigned short* myrow = Sb + (size_t)lane * 64;
#pragma unroll
        for (int s = 0; s < 6; ++s) {
            u32x4 c = *(u32x4*)((char*)myrow + ((s * 16) ^ ((lane & 7) << 4)));
            *(u32x4*)(dstcl + ((size_t)s * NLOC_ + loc) * 8) = c;
        }
    } else {
        int s0 = base - b * DHW_;
#pragma unroll
        for (int mt = 0; mt < 3; ++mt) {
#pragma unroll
            for (int r = 0; r < 4; ++r) {
                int oc = mt * 16 + 4 * g + r;
                float bb = bias[oc];
#pragma unroll
                for (int nt = 0; nt < 4; ++nt) {
                    size_t addr = ((size_t)b * C_ + oc) * DHW_ + (s0 + nt * 16 + li);
                    float v = acc[mt][nt][r] + bb;
                    if (LEAKY) v = (v >= 0.0f) ? v : 0.1f * v;
                    if (RESID) v += resid[addr];
                    dstf[addr] = v;
                }
            }
        }
    }
}

extern "C" void kernel_launch(void* const* d_in, const int* in_sizes, int n_in,
                              void* d_out, int out_size, void* d_ws, size_t ws_size,
                              hipStream_t stream) {
    const float* x      = (const float*)d_in[0];
    const float* w_off0 = (const float*)d_in[1];
    const float* b_off0 = (const float*)d_in[2];
    const float* w0     = (const float*)d_in[3];
    const float* b0     = (const float*)d_in[4];
    const float* w_off1 = (const float*)d_in[5];
    const float* b_off1 = (const float*)d_in[6];
    const float* w1     = (const float*)d_in[7];
    const float* b1     = (const float*)d_in[8];
    float* out = (float*)d_out;

    // ws: xcl (48*NLOC bf16) | hcl (48*NLOC bf16) | wf_off | wf_conv
    unsigned short* xcl = (unsigned short*)d_ws;
    unsigned short* hcl = xcl + (size_t)NLOC_ * 48;
    unsigned short* wf_off  = hcl + (size_t)NLOC_ * 48;
    unsigned short* wf_conv = wf_off + 27 * 4 * 1024;

    dim3 blk128(128), blk256(256);
    int nblk = NLOC_ / 64;    // 2352 (divisible by 8)

    to_cl_kernel<<<NLOC_ / 256, blk256, 0, stream>>>(x, xcl);

    // --- layer 0 (fused offconv+deform, channels-last bf16 out) ---
    repack_frag_kernel<<<(27 * 4 * 1024 + 255) / 256, blk256, 0, stream>>>(w_off0, wf_off, OFFC_, 4);
    repack_frag_kernel<<<(27 * 3 * 1024 + 255) / 256, blk256, 0, stream>>>(w0, wf_conv, C_, 3);
    fused_layer<1, 0, 1><<<nblk, blk128, 0, stream>>>(xcl, wf_off, b_off0, wf_conv, b0,
                                                      nullptr, nullptr, hcl);

    // --- layer 1 (fused, fp32 out + residual) ---
    repack_frag_kernel<<<(27 * 4 * 1024 + 255) / 256, blk256, 0, stream>>>(w_off1, wf_off, OFFC_, 4);
    repack_frag_kernel<<<(27 * 3 * 1024 + 255) / 256, blk256, 0, stream>>>(w1, wf_conv, C_, 3);
    fused_layer<0, 1, 0><<<nblk, blk128, 0, stream>>>(hcl, wf_off, b_off1, wf_conv, b1,
                                                      x, out, nullptr);
}

// Round 16
// 259.094 us; speedup vs baseline: 1.3063x; 1.0946x over previous
//
#include <hip/hip_runtime.h>
#include <hip/hip_fp16.h>

// (B, nf, D, H, W) = (4, 48, 12, 56, 56), fp32 in/out, FP16 MFMA internally.
// Sampled tensors: SIX fp16 chunk-planes [6][NLOC][8ch] (16B/pixel stride).
// Round 16: round-15 fused structure, but sampled dtype = FP16 so bilinear
// interp runs entirely in packed-fp16 VOP3P (v_pk_fma_f16): 4 VALU per u32
// instead of 13 (bf16 needed 8 unpack + 4 pk f32 + 1 cvt). MFMA switches to
// mfma_f32_16x16x32_f16 (same shape/frag/C-D layout). fp16 also has MORE
// mantissa than bf16 -> accuracy equal or better.
constexpr int B_ = 4, C_ = 48, D_ = 12, H_ = 56, W_ = 56;
constexpr int DHW_ = D_ * H_ * W_;        // 37632
constexpr int NLOC_ = B_ * DHW_;          // 150528 -> 2352 blocks of 128
constexpr int OFFC_ = 54;                 // 27 taps x 2 (dh, dw)
constexpr int NXCD_ = 8;

typedef _Float16 f16x8 __attribute__((ext_vector_type(8)));
typedef float f32x4  __attribute__((ext_vector_type(4)));
typedef float f32x2  __attribute__((ext_vector_type(2)));
typedef unsigned int u32x4 __attribute__((ext_vector_type(4)));
typedef unsigned int u32x2 __attribute__((ext_vector_type(2)));

__device__ __forceinline__ int xcd_swizzle(int bid, int nwg) {
    int xcd = bid % NXCD_, lid = bid / NXCD_;
    int q = nwg / NXCD_, r = nwg % NXCD_;
    return (xcd < r ? xcd * (q + 1) : r * (q + 1) + (xcd - r) * q) + lid;
}

__device__ __forceinline__ unsigned short f2h_u(float f) {
    return __builtin_bit_cast(unsigned short, (_Float16)f);   // RNE
}
__device__ __forceinline__ unsigned int pack_h2(float lo, float hi) {
    return (unsigned int)f2h_u(lo) | ((unsigned int)f2h_u(hi) << 16);
}
__device__ __forceinline__ __half2 bcH(unsigned int u) {
    return __builtin_bit_cast(__half2, u);
}
__device__ __forceinline__ unsigned int bcU(__half2 h) {
    return __builtin_bit_cast(unsigned int, h);
}

// 4-corner bilinear on a 16B chunk (8 fp16 channels), packed-fp16 math:
// 4 VOP3P ops per u32, no unpack/pack at all.
__device__ __forceinline__ u32x4 interp4_h(u32x4 c00, u32x4 c01, u32x4 c10, u32x4 c11,
                                           __half2 w0, __half2 w1, __half2 w2, __half2 w3) {
    u32x4 pv;
#pragma unroll
    for (int u = 0; u < 4; ++u) {
        __half2 r = __hmul2(w0, bcH(c00[u]));
        r = __hfma2(w1, bcH(c01[u]), r);
        r = __hfma2(w2, bcH(c10[u]), r);
        r = __hfma2(w3, bcH(c11[u]), r);
        pv[u] = bcU(r);
    }
    return pv;
}

// Pack weights into MFMA A-fragment order (fp16):
// wf[k][mt][ks][lane][i] = W[oc=mt*16+(lane&15)][c=ks*32+8*(lane>>4)+i][tap k]
__global__ void __launch_bounds__(256) repack_frag_kernel(
    const float* __restrict__ w, unsigned short* __restrict__ wf, int OC, int MT) {
    int t = blockIdx.x * 256 + threadIdx.x;
    int total = 27 * MT * 1024;
    if (t >= total) return;
    int i    = t & 7;
    int lane = (t >> 3) & 63;
    int ks   = (t >> 9) & 1;
    int mt   = (t >> 10) % MT;
    int k    = t / (MT << 10);
    int oc = mt * 16 + (lane & 15);
    int c  = ks * 32 + 8 * (lane >> 4) + i;
    float v = (oc < OC && c < 48) ? w[((size_t)oc * 48 + c) * 27 + k] : 0.0f;
    wf[t] = f2h_u(v);
}

// fp32 [B][48][DHW] -> fp16 chunk-planes [6][NLOC][8].
__global__ void __launch_bounds__(256) to_cl_kernel(const float* __restrict__ x,
                                                    unsigned short* __restrict__ xcl) {
    int loc = blockIdx.x * 256 + threadIdx.x;
    int b = loc / DHW_, s = loc - b * DHW_;
    const float* xp = x + (size_t)b * (C_ * DHW_) + s;
#pragma unroll
    for (int q = 0; q < 6; ++q) {
        float v[8];
#pragma unroll
        for (int u = 0; u < 8; ++u) v[u] = xp[(size_t)(q * 8 + u) * DHW_];
        u32x4 o;
#pragma unroll
        for (int u = 0; u < 4; ++u)
            o[u] = pack_h2(v[2 * u], v[2 * u + 1]);
        *(u32x4*)(xcl + ((size_t)q * NLOC_ + loc) * 8) = o;   // 16B/lane dense
    }
}

// ---------------- fused layer: offconv (phase A) + deform (phase B) -------------
// Block = 128 = 2 waves sharing 64 locations; wave w does taps k === w (mod 2)
// in both phases. Offsets handed A->B through OFT (packed fp16 pairs).
template <int LEAKY, int RESID, int CLOUT>
__global__ void __launch_bounds__(128) fused_layer(
    const unsigned short* __restrict__ scl,   // [6][NLOC][8] fp16 chunk-planes
    const unsigned short* __restrict__ wfo,   // offconv frag weights (fp16), MT=4
    const float* __restrict__ bo,             // [54]
    const unsigned short* __restrict__ wfc,   // deform frag weights (fp16), MT=3
    const float* __restrict__ bias,           // [48]
    const float* __restrict__ resid,          // [B][48][DHW] fp32 (RESID)
    float* __restrict__ dstf,                 // [B][48][DHW] fp32 (!CLOUT)
    unsigned short* __restrict__ dstcl) {     // [6][NLOC][8] fp16 (CLOUT)
    __shared__ unsigned short S[2][64][64];   // 16KB staging + exchange
    __shared__ unsigned int OFT[64][29];      // 7.4KB offsets as fp16 pairs
                                              // (stride 29: gcd(29,32)=1 -> conflict-free)
    int tid = threadIdx.x, wid = tid >> 6, lane = tid & 63;
    int base = xcd_swizzle(blockIdx.x, gridDim.x) * 64;
    int loc = base + lane;
    int b = loc / DHW_;
    int sp = loc - b * DHW_;
    int w = sp % W_; int t1 = sp / W_;
    int h = t1 % H_; int d = t1 / H_;
    int g = lane >> 4, li = lane & 15, l7 = lane & 7;

    u32x4 z = {0, 0, 0, 0};
    *(u32x4*)&S[wid][lane][(6 ^ l7) * 8] = z;   // K-pad channels 48..63
    *(u32x4*)&S[wid][lane][(7 ^ l7) * 8] = z;

    const u32x4* plane[6];
#pragma unroll
    for (int q = 0; q < 6; ++q)
        plane[q] = (const u32x4*)(scl + ((size_t)q * NLOC_ + (size_t)b * DHW_) * 8);

    // ================= phase A: offset conv (54 channels) =================
    {
        f32x4 acc[4][4];
#pragma unroll
        for (int mt = 0; mt < 4; ++mt)
#pragma unroll
            for (int nt = 0; nt < 4; ++nt) acc[mt][nt] = (f32x4){0.f, 0.f, 0.f, 0.f};

#pragma unroll 1
        for (int i = 0; i < 14; ++i) {
            int k = wid + 2 * i;
            if (k >= 27) break;
            int kd = k / 9 - 1, kh = (k / 3) % 3 - 1, kw = k % 3 - 1;
            int pd = d + kd, ph = h + kh, pw = w + kw;
            bool valid = (pd >= 0) & (pd < D_) & (ph >= 0) & (ph < H_) &
                         (pw >= 0) & (pw < W_);
            if (!__any((int)valid)) continue;   // whole tap contributes zero
            int pdc = min(max(pd, 0), D_ - 1);
            int phc = min(max(ph, 0), H_ - 1);
            int pwc = min(max(pw, 0), W_ - 1);
            int pix = (pdc * H_ + phc) * W_ + pwc;
            u32x4 pv[6];
#pragma unroll
            for (int cc = 0; cc < 6; ++cc) pv[cc] = plane[cc][pix];   // coalesced
#pragma unroll
            for (int cc = 0; cc < 6; ++cc) {
                if (!valid) pv[cc] = z;
                *(u32x4*)&S[wid][lane][(cc ^ l7) * 8] = pv[cc];
            }
            const unsigned short* wk = wfo + (size_t)k * 4096 + lane * 8;
            f16x8 a[4][2];
#pragma unroll
            for (int mt = 0; mt < 4; ++mt)
#pragma unroll
                for (int ks = 0; ks < 2; ++ks)
                    a[mt][ks] = *(const f16x8*)&wk[(mt * 2 + ks) * 512];
#pragma unroll
            for (int nt = 0; nt < 4; ++nt) {
                const unsigned short* sr = &S[wid][nt * 16 + li][0];
                f16x8 b0 = *(const f16x8*)&sr[((0 + g) ^ l7) * 8];
                f16x8 b1 = *(const f16x8*)&sr[((4 + g) ^ l7) * 8];
#pragma unroll
                for (int mt = 0; mt < 4; ++mt) {
                    acc[mt][nt] = __builtin_amdgcn_mfma_f32_16x16x32_f16(a[mt][0], b0, acc[mt][nt], 0, 0, 0);
                    acc[mt][nt] = __builtin_amdgcn_mfma_f32_16x16x32_f16(a[mt][1], b1, acc[mt][nt], 0, 0, 0);
                }
            }
        }

        // cross-wave reduction through S (two 8KB phases). Barrier FIRST:
        // staging tiles (aliased by XCH) must be dead before the writes.
        float* XCH = (float*)&S[0][0][0];
        __syncthreads();
        if (wid == 1) {
#pragma unroll
            for (int mt = 0; mt < 2; ++mt)
#pragma unroll
                for (int nt = 0; nt < 4; ++nt)
                    *(f32x4*)(XCH + (mt * 4 + nt) * 256 + lane * 4) = acc[mt][nt];
        }
        __syncthreads();
        if (wid == 0) {
#pragma unroll
            for (int mt = 0; mt < 2; ++mt)
#pragma unroll
                for (int nt = 0; nt < 4; ++nt)
                    acc[mt][nt] += *(f32x4*)(XCH + (mt * 4 + nt) * 256 + lane * 4);
        }
        __syncthreads();
        if (wid == 1) {
#pragma unroll
            for (int mt = 2; mt < 4; ++mt)
#pragma unroll
                for (int nt = 0; nt < 4; ++nt)
                    *(f32x4*)(XCH + ((mt - 2) * 4 + nt) * 256 + lane * 4) = acc[mt][nt];
        }
        __syncthreads();
        if (wid == 0) {
#pragma unroll
            for (int mt = 2; mt < 4; ++mt)
#pragma unroll
                for (int nt = 0; nt < 4; ++nt)
                    acc[mt][nt] += *(f32x4*)(XCH + ((mt - 2) * 4 + nt) * 256 + lane * 4);
            // OFT[loc][k] = packed fp16 (odh, odw) with bias. oc = mt*16+4g+2rp
            // is always even; k = oc/2 = mt*8+2g+rp.
#pragma unroll
            for (int mt = 0; mt < 4; ++mt)
#pragma unroll
                for (int nt = 0; nt < 4; ++nt)
#pragma unroll
                    for (int rp = 0; rp < 2; ++rp) {
                        int oc = mt * 16 + 4 * g + 2 * rp;
                        if (oc < OFFC_) {
                            int kk = mt * 8 + 2 * g + rp;
                            OFT[nt * 16 + li][kk] =
                                pack_h2(acc[mt][nt][2 * rp] + bo[oc],
                                        acc[mt][nt][2 * rp + 1] + bo[oc + 1]);
                        }
                    }
        }
        __syncthreads();   // OFT visible to all; exchange traffic fully drained
    }

    // re-init K-pad slots (phase A exchange clobbered S[0]; cheap to do both)
    *(u32x4*)&S[wid][lane][(6 ^ l7) * 8] = z;
    *(u32x4*)&S[wid][lane][(7 ^ l7) * 8] = z;

    // ================= phase B: deformable conv (48 channels) =================
    f32x4 acc[3][4];
#pragma unroll
    for (int mt = 0; mt < 3; ++mt)
#pragma unroll
        for (int nt = 0; nt < 4; ++nt) acc[mt][nt] = (f32x4){0.f, 0.f, 0.f, 0.f};

#pragma unroll 1
    for (int i = 0; i < 14; ++i) {
        int k = wid + 2 * i;
        if (k >= 27) break;
        int kd = k / 9 - 1, kh = (k / 3) % 3 - 1, kw = k % 3 - 1;
        int pd = d + kd;
        bool vd = (pd >= 0) & (pd < D_);
        if (!__any((int)vd)) continue;   // depth-invalid tap group: contributes 0
        int pdc = min(max(pd, 0), D_ - 1);

        unsigned int ou = OFT[lane][k];
        __half2 oh2 = bcH(ou);
        float odh = __low2float(oh2), odw = __high2float(oh2);
        float phf = (float)(h + kh) + odh;
        float pwf = (float)(w + kw) + odw;
        float h0f = floorf(phf), w0f = floorf(pwf);
        float th = phf - h0f, tw = pwf - w0f;
        int h0 = (int)h0f, w0 = (int)w0f;

        int pix[4];
        f32x4 cw;
#pragma unroll
        for (int dh = 0; dh < 2; ++dh) {
            int hh = h0 + dh;
            bool vh = vd & (hh >= 0) & (hh < H_);
            int hhc = min(max(hh, 0), H_ - 1);
            float wh = dh ? th : 1.0f - th;
#pragma unroll
            for (int dw = 0; dw < 2; ++dw) {
                int ww = w0 + dw;
                bool v = vh & (ww >= 0) & (ww < W_);
                int wwc = min(max(ww, 0), W_ - 1);
                float wwt = dw ? tw : 1.0f - tw;
                pix[dh * 2 + dw] = (pdc * H_ + hhc) * W_ + wwc;   // clamped in-bounds
                cw[dh * 2 + dw] = v ? wh * wwt : 0.0f;
            }
        }
        __half2 w0p = __float2half2_rn(cw[0]);
        __half2 w1p = __float2half2_rn(cw[1]);
        __half2 w2p = __float2half2_rn(cw[2]);
        __half2 w3p = __float2half2_rn(cw[3]);

        // two halves of 12 staged 16B gathers (3 chunk-planes x 4 corners)
#pragma unroll
        for (int half = 0; half < 2; ++half) {
            u32x4 st[3][4];
#pragma unroll
            for (int cc = 0; cc < 3; ++cc)
#pragma unroll
                for (int j = 0; j < 4; ++j)
                    st[cc][j] = plane[half * 3 + cc][pix[j]];
#pragma unroll
            for (int cc = 0; cc < 3; ++cc) {
                u32x4 pv = interp4_h(st[cc][0], st[cc][1], st[cc][2], st[cc][3],
                                     w0p, w1p, w2p, w3p);
                *(u32x4*)&S[wid][lane][((half * 3 + cc) ^ l7) * 8] = pv;
            }
        }

        const unsigned short* wk = wfc + (size_t)k * 3072 + lane * 8;
        f16x8 a[3][2];
#pragma unroll
        for (int mt = 0; mt < 3; ++mt)
#pragma unroll
            for (int ks = 0; ks < 2; ++ks)
                a[mt][ks] = *(const f16x8*)&wk[(mt * 2 + ks) * 512];
#pragma unroll
        for (int nt = 0; nt < 4; ++nt) {
            const unsigned short* sr = &S[wid][nt * 16 + li][0];
            f16x8 b0 = *(const f16x8*)&sr[((0 + g) ^ l7) * 8];
            f16x8 b1 = *(const f16x8*)&sr[((4 + g) ^ l7) * 8];
#pragma unroll
            for (int mt = 0; mt < 3; ++mt) {
                acc[mt][nt] = __builtin_amdgcn_mfma_f32_16x16x32_f16(a[mt][0], b0, acc[mt][nt], 0, 0, 0);
                acc[mt][nt] = __builtin_amdgcn_mfma_f32_16x16x32_f16(a[mt][1], b1, acc[mt][nt], 0, 0, 0);
            }
        }
    }

    // cross-wave tap reduction through S[1] (keeps S[0] free for CLOUT
    // transpose). Barrier first: no wave may still be using its staging tile.
    float* XCH = (float*)&S[1][0][0];   // 8KB = 8 groups of 1KB
    __syncthreads();
    if (wid == 1) {
#pragma unroll
        for (int mt = 0; mt < 2; ++mt)
#pragma unroll
            for (int nt = 0; nt < 4; ++nt)
                *(f32x4*)(XCH + (mt * 4 + nt) * 256 + lane * 4) = acc[mt][nt];
    }
    __syncthreads();
    if (wid == 0) {
#pragma unroll
        for (int mt = 0; mt < 2; ++mt)
#pragma unroll
            for (int nt = 0; nt < 4; ++nt)
                acc[mt][nt] += *(f32x4*)(XCH + (mt * 4 + nt) * 256 + lane * 4);
    }
    __syncthreads();
    if (wid == 1) {
#pragma unroll
        for (int nt = 0; nt < 4; ++nt)
            *(f32x4*)(XCH + nt * 256 + lane * 4) = acc[2][nt];
    }
    __syncthreads();
    if (wid == 1) return;
#pragma unroll
    for (int nt = 0; nt < 4; ++nt)
        acc[2][nt] += *(f32x4*)(XCH + nt * 256 + lane * 4);

    if (CLOUT) {
        // Transpose D-tile through wave0's (now free) S[0] tile, then write
        // fp16 chunk-planes: 16B/lane dense per plane, fully coalesced.
        unsigned short* Sb = &S[0][0][0];   // row stride 64 u16 = 128 B
#pragma unroll
        for (int mt = 0; mt < 3; ++mt) {
#pragma unroll
            for (int nt = 0; nt < 4; ++nt) {
                float v[4];
#pragma unroll
                for (int r = 0; r < 4; ++r) {
                    int oc = mt * 16 + 4 * g + r;
                    float t = acc[mt][nt][r] + bias[oc];
                    if (LEAKY) t = (t >= 0.f) ? t : 0.1f * t;
                    v[r] = t;
                }
                int row = nt * 16 + li;
                int colb = (mt * 32 + 8 * g) ^ ((li & 7) << 4);
                u32x2 pp = {pack_h2(v[0], v[1]), pack_h2(v[2], v[3])};
                *(u32x2*)((char*)(Sb + (size_t)row * 64) + colb) = pp;
            }
        }
        unsigned short* myrow = Sb + (size_t)lane * 64;
#pragma unroll
        for (int s = 0; s < 6; ++s) {
            u32x4 c = *(u32x4*)((char*)myrow + ((s * 16) ^ ((lane & 7) << 4)));
            *(u32x4*)(dstcl + ((size_t)s * NLOC_ + loc) * 8) = c;
        }
    } else {
        int s0 = base - b * DHW_;
#pragma unroll
        for (int mt = 0; mt < 3; ++mt) {
#pragma unroll
            for (int r = 0; r < 4; ++r) {
                int oc = mt * 16 + 4 * g + r;
                float bb = bias[oc];
#pragma unroll
                for (int nt = 0; nt < 4; ++nt) {
                    size_t addr = ((size_t)b * C_ + oc) * DHW_ + (s0 + nt * 16 + li);
                    float v = acc[mt][nt][r] + bb;
                    if (LEAKY) v = (v >= 0.0f) ? v : 0.1f * v;
                    if (RESID) v += resid[addr];
                    dstf[addr] = v;
                }
            }
        }
    }
}

extern "C" void kernel_launch(void* const* d_in, const int* in_sizes, int n_in,
                              void* d_out, int out_size, void* d_ws, size_t ws_size,
                              hipStream_t stream) {
    const float* x      = (const float*)d_in[0];
    const float* w_off0 = (const float*)d_in[1];
    const float* b_off0 = (const float*)d_in[2];
    const float* w0     = (const float*)d_in[3];
    const float* b0     = (const float*)d_in[4];
    const float* w_off1 = (const float*)d_in[5];
    const float* b_off1 = (const float*)d_in[6];
    const float* w1     = (const float*)d_in[7];
    const float* b1     = (const float*)d_in[8];
    float* out = (float*)d_out;

    // ws: xcl (48*NLOC fp16) | hcl (48*NLOC fp16) | wf_off | wf_conv
    unsigned short* xcl = (unsigned short*)d_ws;
    unsigned short* hcl = xcl + (size_t)NLOC_ * 48;
    unsigned short* wf_off  = hcl + (size_t)NLOC_ * 48;
    unsigned short* wf_conv = wf_off + 27 * 4 * 1024;

    dim3 blk128(128), blk256(256);
    int nblk = NLOC_ / 64;    // 2352 (divisible by 8)

    to_cl_kernel<<<NLOC_ / 256, blk256, 0, stream>>>(x, xcl);

    // --- layer 0 (fused offconv+deform, channels-last fp16 out) ---
    repack_frag_kernel<<<(27 * 4 * 1024 + 255) / 256, blk256, 0, stream>>>(w_off0, wf_off, OFFC_, 4);
    repack_frag_kernel<<<(27 * 3 * 1024 + 255) / 256, blk256, 0, stream>>>(w0, wf_conv, C_, 3);
    fused_layer<1, 0, 1><<<nblk, blk128, 0, stream>>>(xcl, wf_off, b_off0, wf_conv, b0,
                                                      nullptr, nullptr, hcl);

    // --- layer 1 (fused, fp32 out + residual) ---
    repack_frag_kernel<<<(27 * 4 * 1024 + 255) / 256, blk256, 0, stream>>>(w_off1, wf_off, OFFC_, 4);
    repack_frag_kernel<<<(27 * 3 * 1024 + 255) / 256, blk256, 0, stream>>>(w1, wf_conv, C_, 3);
    fused_layer<0, 1, 0><<<nblk, blk128, 0, stream>>>(hcl, wf_off, b_off1, wf_conv, b1,
                                                      x, out, nullptr);
}